// Round 3
// baseline (361.267 us; speedup 1.0000x reference)
//
#include <hip/hip_runtime.h>
#include <stdint.h>

#define BATCH 256
#define M 512
#define N 512
#define K 128

typedef int int4v __attribute__((ext_vector_type(4)));

// One block per batch (grid=256, 1 block/CU). 512 threads = 8 waves.
// Inputs arrive as INT32 (harness widens integer dtypes: "integer -> const int*").
// Stage: read a[b], b[b] int32 coalesced, pack low bytes -> int8 in
// XOR-swizzled LDS (64KB + 64KB). Compute: wave w owns the 512x64 output
// strip at columns w*64, iterating 8 row-supertiles of 64x64 with
// mfma_i32_16x16x64_i8 (K=128 -> 2 k-steps), B-fragments hoisted.
__global__ __launch_bounds__(512, 2) void bmm_s8s8_f32_kernel(
    const int* __restrict__ A32,       // [BATCH, M, K] int32 (values in [-128,127])
    const int* __restrict__ B32,       // [BATCH, N, K] int32
    const float* __restrict__ alpha_p, // scalar
    float* __restrict__ O)             // [BATCH, M, N] fp32
{
    __shared__ int8_t As[M * K]; // 64 KB
    __shared__ int8_t Bs[N * K]; // 64 KB

    const int tid = threadIdx.x;
    const int bat = blockIdx.x;

    const int* Ag = A32 + (size_t)bat * (M * K);
    const int* Bg = B32 + (size_t)bat * (N * K);

    // ---- Stage + pack: 16384 dword-groups per matrix, 512 threads x 32 iters.
    // Lane loads 16B (4 int32), packs to one dword of 4 int8, writes LDS.
    // LDS layout: row-major [row][128] int8 with 16B-chunk XOR swizzle:
    //   byte addr = row*128 + (chunk ^ (row & 7))*16 + sub*4
    // Swizzled dword writes within a row are a bijection on banks -> 2 rows
    // per wave = 2 lanes/bank = free (m136).
#pragma unroll 4
    for (int i = 0; i < 32; ++i) {
        const int g   = i * 512 + tid;   // dword-group 0..16383
        const int row = g >> 5;          // 32 groups per 128-int32 row
        const int kg  = g & 31;
        const int kc  = kg >> 2;         // 16B chunk 0..7
        const int sub = kg & 3;
        const int kcs = kc ^ (row & 7);

        int4v wa = *(const int4v*)(Ag + (size_t)g * 4);
        int4v wb = *(const int4v*)(Bg + (size_t)g * 4);
        const int pa = (wa.x & 0xff) | ((wa.y & 0xff) << 8) |
                       ((wa.z & 0xff) << 16) | (wa.w << 24);
        const int pb = (wb.x & 0xff) | ((wb.y & 0xff) << 8) |
                       ((wb.z & 0xff) << 16) | (wb.w << 24);
        *(int*)(As + row * 128 + kcs * 16 + sub * 4) = pa;
        *(int*)(Bs + row * 128 + kcs * 16 + sub * 4) = pb;
    }
    __syncthreads();

    const int lane = tid & 63;
    const int wave = tid >> 6;
    const int l15  = lane & 15;
    const int quad = lane >> 4;
    const int sn   = wave; // supertile column (n-offset sn*64)

    // Hoist B fragments for this wave's column strip.
    // Operand layout: lane holds row (l15-indexed) x 16B k-chunk (quad);
    // exact slot->k bijection cancels between A and B fragments.
    int4v bf[2][4];
#pragma unroll
    for (int ks = 0; ks < 2; ++ks)
#pragma unroll
        for (int j = 0; j < 4; ++j) {
            const int rb = sn * 64 + j * 16 + l15;
            const int kc = (ks * 4 + quad) ^ (rb & 7);
            bf[ks][j] = *(const int4v*)(Bs + rb * 128 + kc * 16);
        }

    const float alpha = *alpha_p;

    for (int sm = 0; sm < 8; ++sm) {
        int4v af[2][4];
#pragma unroll
        for (int ks = 0; ks < 2; ++ks)
#pragma unroll
            for (int i = 0; i < 4; ++i) {
                const int ra = sm * 64 + i * 16 + l15;
                const int kc = (ks * 4 + quad) ^ (ra & 7);
                af[ks][i] = *(const int4v*)(As + ra * 128 + kc * 16);
            }

        int4v acc[4][4];
#pragma unroll
        for (int i = 0; i < 4; ++i)
#pragma unroll
            for (int j = 0; j < 4; ++j)
                acc[i][j] = (int4v){0, 0, 0, 0};

#pragma unroll
        for (int ks = 0; ks < 2; ++ks)
#pragma unroll
            for (int i = 0; i < 4; ++i)
#pragma unroll
                for (int j = 0; j < 4; ++j)
                    acc[i][j] = __builtin_amdgcn_mfma_i32_16x16x64_i8(
                        af[ks][i], bf[ks][j], acc[i][j], 0, 0, 0);

        // C/D layout: col = lane&15 (n), row = quad*4 + reg (m). [m89/m121-128]
        float* Ob = O + ((size_t)bat * M + sm * 64 + quad * 4) * N + sn * 64 + l15;
#pragma unroll
        for (int i = 0; i < 4; ++i)
#pragma unroll
            for (int r = 0; r < 4; ++r) {
                float* rowp = Ob + (size_t)(i * 16 + r) * N;
#pragma unroll
                for (int j = 0; j < 4; ++j)
                    rowp[j * 16] = alpha * (float)acc[i][j][r];
            }
    }
}

extern "C" void kernel_launch(void* const* d_in, const int* in_sizes, int n_in,
                              void* d_out, int out_size, void* d_ws, size_t ws_size,
                              hipStream_t stream) {
    const int*   a     = (const int*)d_in[0];
    const int*   b     = (const int*)d_in[1];
    const float* alpha = (const float*)d_in[2];
    float*       out   = (float*)d_out;

    dim3 grid(BATCH);
    dim3 block(512);
    bmm_s8s8_f32_kernel<<<grid, block, 0, stream>>>(a, b, alpha, out);
}